// Round 7
// baseline (874.471 us; speedup 1.0000x reference)
//
#include <hip/hip_runtime.h>
#include <math.h>

#define BATCH 2048
#define CH 512
#define N_COARSE 256
#define F_FINE 256
#define K_TOP 4
#define OUT_STRIDE 65537  // 1 + N*F

typedef unsigned short ushort_t;
typedef __bf16 bf16x8 __attribute__((ext_vector_type(8)));
typedef float f32x4 __attribute__((ext_vector_type(4)));

typedef __attribute__((address_space(3))) unsigned int lds_uint;
typedef __attribute__((address_space(1))) unsigned int gl_uint;

// async global->LDS, 16B per lane; LDS dest = wave-uniform base + lane*16
__device__ __forceinline__ void gload_lds16(const ushort_t* g, ushort_t* l) {
    __builtin_amdgcn_global_load_lds((const gl_uint*)g, (lds_uint*)l, 16, 0, 0);
}

__device__ __forceinline__ float gelu_tanh(float x) {
    float x3 = x * x * x;
    float t = tanhf(0.7978845608028654f * (x + 0.044715f * x3));
    return 0.5f * x * (1.0f + t);
}

__device__ __forceinline__ ushort_t f2bf(float f) {
    unsigned u = __float_as_uint(f);
    unsigned r = (u + 0x7FFF + ((u >> 16) & 1)) >> 16;
    return (ushort_t)r;
}
__device__ __forceinline__ float bf2f(ushort_t h) {
    return __uint_as_float(((unsigned)h) << 16);
}

struct Params {
    const float *x, *in_g, *in_b, *nop_w, *nop_b;
    const float *c_w1, *c_b1, *c_w2, *c_b2, *c_w3, *c_b3;
    const float *emb, *emb_g, *emb_b;
    const float *f_w1, *f_b1, *f_w2, *f_b2, *f_w3, *f_b3;
    float *coarse, *out, *cvals;
    ushort_t *xnsp, *h1sp, *h2sp, *e_bf, *fh1_bf, *fh2_bf;
    ushort_t *wt1, *wt2, *wt3, *cwt1, *cwt2, *cwt3;
    int *idxb;
};

// ---- device-scope grid barrier (all blocks resident: grid<=2/CU via launch_bounds) ----
__device__ __forceinline__ void gbar(int* cnt, int target) {
    __syncthreads();
    if (threadIdx.x == 0) {
        __threadfence();                 // release: make prior writes device-visible
        atomicAdd(cnt, 1);
        while (__hip_atomic_load(cnt, __ATOMIC_RELAXED, __HIP_MEMORY_SCOPE_AGENT) < target)
            __builtin_amdgcn_s_sleep(8);
        __threadfence();                 // acquire: see other blocks' writes
    }
    __syncthreads();
}

// ---------------- prep unit: u<896 fine convT; u<1536 coarse convT hi/lo; else LN+no_op ----
__device__ __forceinline__ void prep_unit(const Params& p, int u, void* smemraw) {
    float (*s)[33] = (float(*)[33])smemraw;
    int t = threadIdx.x;
    if (u < 1536) {
        const float* W; ushort_t* Wt; int Kd, Nd, gx, gy; bool split;
        if (u < 512)       { W=p.f_w1; Wt=p.wt1; Kd=1024; Nd=512; gx=u&15; gy=u>>4; split=false; }
        else if (u < 768)  { int v=u-512;  W=p.f_w2; Wt=p.wt2; Kd=512; Nd=512; gx=v&15; gy=v>>4; split=false; }
        else if (u < 896)  { int v=u-768;  W=p.f_w3; Wt=p.wt3; Kd=512; Nd=256; gx=v&7;  gy=v>>3; split=false; }
        else if (u < 1152) { int v=u-896;  W=p.c_w1; Wt=p.cwt1; Kd=512; Nd=512; gx=v&15; gy=v>>4; split=true; }
        else if (u < 1408) { int v=u-1152; W=p.c_w2; Wt=p.cwt2; Kd=512; Nd=512; gx=v&15; gy=v>>4; split=true; }
        else               { int v=u-1408; W=p.c_w3; Wt=p.cwt3; Kd=512; Nd=256; gx=v&7;  gy=v>>3; split=true; }
        int tx = t & 31, ty = t >> 5;
        int n0 = gx * 32, k0 = gy * 32;
        #pragma unroll
        for (int i = 0; i < 4; ++i) {
            int r = ty + i * 8;
            s[r][tx] = W[(size_t)(k0 + r) * Nd + n0 + tx];
        }
        __syncthreads();
        if (!split) {
            #pragma unroll
            for (int i = 0; i < 4; ++i) {
                int r = ty + i * 8;
                Wt[(size_t)(n0 + r) * Kd + k0 + tx] = f2bf(s[tx][r]);
            }
        } else {
            #pragma unroll
            for (int i = 0; i < 4; ++i) {
                int r = ty + i * 8;
                float v = s[tx][r];
                ushort_t h = f2bf(v);
                Wt[(size_t)(n0 + r) * 1024 + k0 + tx] = h;
                Wt[(size_t)(n0 + r) * 1024 + 512 + k0 + tx] = f2bf(v - bf2f(h));
            }
        }
    } else {
        float* red = &s[0][0];
        int row = u - 1536;
        int lane = t & 63, wave = t >> 6;
        const float* xr = p.x + (size_t)row * CH;
        float v0 = xr[t], v1 = xr[t + 256];
        float sm = v0 + v1, ss = v0 * v0 + v1 * v1;
        #pragma unroll
        for (int off = 32; off; off >>= 1) { sm += __shfl_xor(sm, off); ss += __shfl_xor(ss, off); }
        if (lane == 0) { red[wave] = sm; red[4 + wave] = ss; }
        __syncthreads();
        sm = red[0] + red[1] + red[2] + red[3];
        ss = red[4] + red[5] + red[6] + red[7];
        float mean = sm * (1.0f / CH);
        float var = ss * (1.0f / CH) - mean * mean;
        float rsq = rsqrtf(var + 1e-5f);
        float xn0 = (v0 - mean) * rsq * p.in_g[t] + p.in_b[t];
        float xn1 = (v1 - mean) * rsq * p.in_g[t + 256] + p.in_b[t + 256];
        ushort_t* xr2 = p.xnsp + (size_t)row * 1024;
        ushort_t h0 = f2bf(xn0), h1v = f2bf(xn1);
        xr2[t] = h0; xr2[t + 256] = h1v;
        xr2[512 + t] = f2bf(xn0 - bf2f(h0));
        xr2[512 + t + 256] = f2bf(xn1 - bf2f(h1v));
        float d = xn0 * p.nop_w[t] + xn1 * p.nop_w[t + 256];
        #pragma unroll
        for (int off = 32; off; off >>= 1) d += __shfl_xor(d, off);
        __syncthreads();
        if (lane == 0) red[wave] = d;
        __syncthreads();
        if (t == 0) p.out[(size_t)row * OUT_STRIDE] = red[0] + red[1] + red[2] + red[3] + p.nop_b[0];
    }
    __syncthreads();   // protect smem across grid-stride iterations
}

// ---------------- coarse GEMM tile: MT=32, 3-term split K=1536, global_load_lds dbuf ----
// OUTM 1: split hi/lo bf16+gelu stride 1024.   OUTM 2: f32 (+bias).
template<int NT, int OUTM>
__device__ __forceinline__ void coarse_tile(const ushort_t* __restrict__ A1,
        const ushort_t* __restrict__ Wt, const float* __restrict__ bias,
        void* __restrict__ Cout, int Nd, int n0, int m0, void* smemraw)
{
    constexpr int MT = 32;
    constexpr int FJ = NT / 32;
    ushort_t (*As)[MT * 32] = (ushort_t(*)[MT * 32])smemraw;
    ushort_t (*Bs)[NT * 32] = (ushort_t(*)[NT * 32])((char*)smemraw + 2 * MT * 32 * 2);
    int t = threadIdx.x;
    int wave = t >> 6, lane = t & 63;
    int wm = (wave & 1) * 16, wn = (wave >> 1) * (NT / 2);
    int lr = lane & 15, quad = lane >> 4;
    int wbase = wave * 64;

    f32x4 acc[FJ] = {};

    auto stageAB = [&](int k0, int pp) {
        int aoff = (k0 >= 1024) ? k0 - 512 : (k0 & 511);
        int woff = (k0 >= 1024) ? k0 - 1024 : k0;
        if (t < MT * 4) {   // waves 0,1 stage A (32 rows x 32 k)
            int r = t >> 2, q = (t & 3) * 8;
            gload_lds16(A1 + (size_t)(m0 + r) * 1024 + aoff + q, &As[pp][wbase * 8]);
        }
        constexpr int BL = NT * 4;
        if constexpr (BL >= 256) {
            gload_lds16(Wt + (size_t)(n0 + (t >> 2)) * 1024 + woff + (t & 3) * 8,
                        &Bs[pp][wbase * 8]);
        } else {
            if (t < BL)
                gload_lds16(Wt + (size_t)(n0 + (t >> 2)) * 1024 + woff + (t & 3) * 8,
                            &Bs[pp][wbase * 8]);
        }
    };

    stageAB(0, 0);
    int pbuf = 0;
    for (int s = 0; s < 48; ++s) {
        __syncthreads();                         // drains vmcnt: buffer pbuf ready
        if (s + 1 < 48) stageAB((s + 1) * 32, pbuf ^ 1);
        bf16x8 af = *(const bf16x8*)&As[pbuf][(wm + lr) * 32 + quad * 8];
        bf16x8 bfr[FJ];
        #pragma unroll
        for (int j = 0; j < FJ; ++j)
            bfr[j] = *(const bf16x8*)&Bs[pbuf][(wn + j * 16 + lr) * 32 + quad * 8];
        #pragma unroll
        for (int j = 0; j < FJ; ++j)
            acc[j] = __builtin_amdgcn_mfma_f32_16x16x32_bf16(af, bfr[j], acc[j], 0, 0, 0);
        pbuf ^= 1;
    }

    #pragma unroll
    for (int j = 0; j < FJ; ++j) {
        int col = n0 + wn + j * 16 + lr;
        float bvv = bias[col];
        #pragma unroll
        for (int r = 0; r < 4; ++r) {
            int row = m0 + wm + quad * 4 + r;
            float val = acc[j][r] + bvv;
            if (OUTM == 1) {
                float gv = gelu_tanh(val);
                ushort_t h = f2bf(gv);
                ((ushort_t*)Cout)[(size_t)row * 1024 + col] = h;
                ((ushort_t*)Cout)[(size_t)row * 1024 + 512 + col] = f2bf(gv - bf2f(h));
            } else {
                ((float*)Cout)[(size_t)row * Nd + col] = val;
            }
        }
    }
    __syncthreads();   // protect smem before next phase/iteration
}

// ---------------- topk unit: top-4 of one coarse row + gather+LN of 4 emb rows -> bf16 ----
__device__ __forceinline__ void topk_unit(const Params& p, int brow, void* smemraw) {
    int* sidx = (int*)smemraw;
    int t = threadIdx.x;
    int wave = t >> 6, lane = t & 63;
    if (wave == 0) {
        const float* cr = p.coarse + (size_t)brow * N_COARSE;
        float v[4]; int id[4];
        #pragma unroll
        for (int j = 0; j < 4; ++j) { v[j] = cr[lane + 64 * j]; id[j] = lane + 64 * j; }
        #pragma unroll
        for (int r = 0; r < K_TOP; ++r) {
            float bv = v[0]; int bi = id[0];
            #pragma unroll
            for (int j = 1; j < 4; ++j)
                if (v[j] > bv || (v[j] == bv && id[j] < bi)) { bv = v[j]; bi = id[j]; }
            #pragma unroll
            for (int off = 32; off; off >>= 1) {
                float ov = __shfl_xor(bv, off); int oi = __shfl_xor(bi, off);
                if (ov > bv || (ov == bv && oi < bi)) { bv = ov; bi = oi; }
            }
            if ((bi & 63) == lane) v[bi >> 6] = -INFINITY;
            if (lane == 0) {
                sidx[r] = bi;
                p.idxb[brow * K_TOP + r] = bi;
                p.cvals[brow * K_TOP + r] = bv;
            }
        }
    }
    __syncthreads();
    int n = sidx[wave];
    const float* er = p.emb + (size_t)n * CH + lane * 8;
    float4 u0 = *(const float4*)er;
    float4 u1 = *(const float4*)(er + 4);
    float s  = u0.x + u0.y + u0.z + u0.w + u1.x + u1.y + u1.z + u1.w;
    float ss = u0.x * u0.x + u0.y * u0.y + u0.z * u0.z + u0.w * u0.w
             + u1.x * u1.x + u1.y * u1.y + u1.z * u1.z + u1.w * u1.w;
    #pragma unroll
    for (int off = 32; off; off >>= 1) { s += __shfl_xor(s, off); ss += __shfl_xor(ss, off); }
    float mean = s * (1.0f / CH);
    float var = ss * (1.0f / CH) - mean * mean;
    float rsq = rsqrtf(var + 1e-5f);
    float4 g0 = *(const float4*)(p.emb_g + lane * 8), g1 = *(const float4*)(p.emb_g + lane * 8 + 4);
    float4 b0 = *(const float4*)(p.emb_b + lane * 8), b1 = *(const float4*)(p.emb_b + lane * 8 + 4);
    uint4 pk;
    pk.x = (unsigned)f2bf((u0.x - mean) * rsq * g0.x + b0.x) |
           ((unsigned)f2bf((u0.y - mean) * rsq * g0.y + b0.y) << 16);
    pk.y = (unsigned)f2bf((u0.z - mean) * rsq * g0.z + b0.z) |
           ((unsigned)f2bf((u0.w - mean) * rsq * g0.w + b0.w) << 16);
    pk.z = (unsigned)f2bf((u1.x - mean) * rsq * g1.x + b1.x) |
           ((unsigned)f2bf((u1.y - mean) * rsq * g1.y + b1.y) << 16);
    pk.w = (unsigned)f2bf((u1.z - mean) * rsq * g1.z + b1.z) |
           ((unsigned)f2bf((u1.w - mean) * rsq * g1.w + b1.w) << 16);
    *(uint4*)(p.e_bf + (size_t)(brow * K_TOP + wave) * CH + lane * 8) = pk;
    __syncthreads();   // protect sidx across grid-stride iterations
}

// ---- background scatter unit: one (b, cx) chunk of the permuted output ----
template<bool SKIP>
__device__ __forceinline__ void bg_scatter_unit(const float* __restrict__ coarse,
                                                const int* __restrict__ idxb,
                                                float* __restrict__ out, int gu) {
    const float LOG_F = 5.545177444479562f;
    int b = gu >> 4, cx = gu & 15, t = threadIdx.x;
    int4 ii = SKIP ? *(const int4*)&idxb[b * 4] : make_int4(-1, -1, -1, -1);
    size_t rowb = (size_t)b * OUT_STRIDE + 1;
    const float* cr = coarse + (size_t)b * N_COARSE;
    #pragma unroll
    for (int q = 0; q < 4; ++q) {
        int o = cx * 4096 + q * 1024 + t * 4;
        int n = ((o >> 12) << 4) | ((o >> 4) & 15);
        bool skip = SKIP && ((n == ii.x) | (n == ii.y) | (n == ii.z) | (n == ii.w));
        if (!skip) {
            float base = cr[n] - LOG_F;
            float* op = out + rowb + o;
            __builtin_nontemporal_store(base, op + 0);
            __builtin_nontemporal_store(base, op + 1);
            __builtin_nontemporal_store(base, op + 2);
            __builtin_nontemporal_store(base, op + 3);
        }
    }
}

// ---------------- fused front-end: prep -> c1 -> c2 -> c3 -> topk (+bg scatter tail) ----
__global__ __launch_bounds__(256, 2) void fused_front_kernel(Params p, int* barcnt) {
    __shared__ __align__(16) unsigned char smem[12544];
    int nb = (int)gridDim.x;     // 512; 2 blocks/CU guaranteed resident
    for (int u = blockIdx.x; u < 3584; u += nb) prep_unit(p, u, smem);
    gbar(barcnt, nb);
    for (int u = blockIdx.x; u < 512; u += nb)
        coarse_tile<64, 1>(p.xnsp, p.cwt1, p.c_b1, p.h1sp, 512, (u & 7) * 64, (u >> 3) * 32, smem);
    gbar(barcnt, 2 * nb);
    for (int u = blockIdx.x; u < 512; u += nb)
        coarse_tile<64, 1>(p.h1sp, p.cwt2, p.c_b2, p.h2sp, 512, (u & 7) * 64, (u >> 3) * 32, smem);
    gbar(barcnt, 3 * nb);
    for (int u = blockIdx.x; u < 512; u += nb)
        coarse_tile<32, 2>(p.h2sp, p.cwt3, p.c_b3, p.coarse, 256, (u & 7) * 32, (u >> 3) * 32, smem);
    gbar(barcnt, 4 * nb);
    for (int r = blockIdx.x; r < BATCH; r += nb) topk_unit(p, r, smem);
    // bg-scatter units [0, 4096): ALL slabs (idxb may not be globally ready; fh3 overwrites top-k)
    for (int gu = blockIdx.x; gu < 4096; gu += nb)
        bg_scatter_unit<false>(p.coarse, nullptr, p.out, gu);
}

// ---------------- bf16 MFMA GEMM (fine stages), MTxNT tile, BK=32, global_load_lds dbuf ----
// MODE 0: A1 row-major stride Ktot.  MODE 1: concat hi(xnsp)/e.
// OUTM 0: bf16+gelu stride Nd.  OUTM 3: cvals + log_softmax -> permuted out (NT==Nd==256).
// Blocks with blockIdx.y >= gemmY run background-scatter units instead (overlap BW w/ MFMA).
template<int MODE, int MT, int NT, int OUTM>
__global__ __launch_bounds__(256) void mfma_gemm_kernel(
    const ushort_t* __restrict__ A1, const ushort_t* __restrict__ A2,
    const ushort_t* __restrict__ Wt, const float* __restrict__ bias,
    const float* __restrict__ cvals, void* __restrict__ Cout, int Nd, int Ktot,
    const float* __restrict__ coarseB, const int* __restrict__ idxbB,
    float* __restrict__ outB, int gemmY, int suBase)
{
    if ((int)blockIdx.y >= gemmY) {
        int gu = suBase + ((int)blockIdx.y - gemmY) * (int)gridDim.x + (int)blockIdx.x;
        bg_scatter_unit<true>(coarseB, idxbB, outB, gu);
        return;
    }
    constexpr int FI = MT / 32, FJ = NT / 32;
    __shared__ ushort_t As[2][MT * 32];
    __shared__ ushort_t Bs[2][NT * 32];
    __shared__ float mxs[64 * 2];
    __shared__ float ses[64 * 2];
    int t = threadIdx.x;
    int n0 = blockIdx.x * NT, m0 = blockIdx.y * MT;
    int wave = t >> 6, lane = t & 63;
    int wm = (wave & 1) * (MT / 2), wn = (wave >> 1) * (NT / 2);
    int lr = lane & 15, quad = lane >> 4;
    int wbase = wave * 64;

    f32x4 acc[FI][FJ] = {};

    auto stageAB = [&](int k0, int pp) {
        constexpr int AL = MT * 4;
        constexpr int BL = NT * 4;
        if constexpr (AL >= 256) {
            #pragma unroll
            for (int i = 0; i < AL / 256; ++i) {
                int c = i * 256 + t, r = c >> 2, q = (c & 3) * 8;
                int gr = m0 + r;
                const ushort_t* ap;
                if (MODE == 1)      ap = (k0 < 512) ? A1 + (size_t)(gr >> 2) * 1024 + k0 + q
                                                    : A2 + (size_t)gr * 512 + (k0 - 512) + q;
                else                ap = A1 + (size_t)gr * Ktot + k0 + q;
                gload_lds16(ap, &As[pp][(i * 256 + wbase) * 8]);
            }
        } else {
            if (t < AL) {
                int r = t >> 2, q = (t & 3) * 8;
                int gr = m0 + r;
                const ushort_t* ap;
                if (MODE == 1)      ap = (k0 < 512) ? A1 + (size_t)(gr >> 2) * 1024 + k0 + q
                                                    : A2 + (size_t)gr * 512 + (k0 - 512) + q;
                else                ap = A1 + (size_t)gr * Ktot + k0 + q;
                gload_lds16(ap, &As[pp][wbase * 8]);
            }
        }
        if constexpr (BL >= 256) {
            #pragma unroll
            for (int i = 0; i < BL / 256; ++i) {
                int c = i * 256 + t, r = c >> 2, q = (c & 3) * 8;
                gload_lds16(Wt + (size_t)(n0 + r) * Ktot + k0 + q, &Bs[pp][(i * 256 + wbase) * 8]);
            }
        } else {
            if (t < BL) {
                int r = t >> 2, q = (t & 3) * 8;
                gload_lds16(Wt + (size_t)(n0 + r) * Ktot + k0 + q, &Bs[pp][wbase * 8]);
            }
        }
    };

    stageAB(0, 0);
    int steps = Ktot >> 5;
    int p = 0;
    for (int s = 0; s < steps; ++s) {
        __syncthreads();
        if (s + 1 < steps) stageAB((s + 1) * 32, p ^ 1);
        bf16x8 af[FI], bfr[FJ];
        #pragma unroll
        for (int i = 0; i < FI; ++i)
            af[i] = *(const bf16x8*)&As[p][(wm + i * 16 + lr) * 32 + quad * 8];
        #pragma unroll
        for (int j = 0; j < FJ; ++j)
            bfr[j] = *(const bf16x8*)&Bs[p][(wn + j * 16 + lr) * 32 + quad * 8];
        #pragma unroll
        for (int i = 0; i < FI; ++i)
            #pragma unroll
            for (int j = 0; j < FJ; ++j)
                acc[i][j] = __builtin_amdgcn_mfma_f32_16x16x32_bf16(af[i], bfr[j], acc[i][j], 0, 0, 0);
        p ^= 1;
    }

    if (OUTM == 3) {
        float bv[FJ];
        #pragma unroll
        for (int j = 0; j < FJ; ++j) bv[j] = bias[wn + j * 16 + lr];
        int half = wave >> 1;
        float rmx[FI][4];
        #pragma unroll
        for (int i = 0; i < FI; ++i)
            #pragma unroll
            for (int r = 0; r < 4; ++r) {
                float m = -1e30f;
                #pragma unroll
                for (int j = 0; j < FJ; ++j) m = fmaxf(m, acc[i][j][r] + bv[j]);
                #pragma unroll
                for (int mk = 1; mk < 16; mk <<= 1) m = fmaxf(m, __shfl_xor(m, mk));
                if (lr == 0) mxs[(wm + i * 16 + quad * 4 + r) * 2 + half] = m;
            }
        __syncthreads();
        #pragma unroll
        for (int i = 0; i < FI; ++i)
            #pragma unroll
            for (int r = 0; r < 4; ++r) {
                int rl = wm + i * 16 + quad * 4 + r;
                rmx[i][r] = fmaxf(mxs[rl * 2], mxs[rl * 2 + 1]);
            }
        #pragma unroll
        for (int i = 0; i < FI; ++i)
            #pragma unroll
            for (int r = 0; r < 4; ++r) {
                float sv = 0.f;
                #pragma unroll
                for (int j = 0; j < FJ; ++j) sv += expf(acc[i][j][r] + bv[j] - rmx[i][r]);
                #pragma unroll
                for (int mk = 1; mk < 16; mk <<= 1) sv += __shfl_xor(sv, mk);
                if (lr == 0) ses[(wm + i * 16 + quad * 4 + r) * 2 + half] = sv;
            }
        __syncthreads();
        #pragma unroll
        for (int i = 0; i < FI; ++i)
            #pragma unroll
            for (int r = 0; r < 4; ++r) {
                int rl = wm + i * 16 + quad * 4 + r;
                float se = ses[rl * 2] + ses[rl * 2 + 1];
                float addc = cvals[m0 + rl] - rmx[i][r] - logf(se);
                int m = m0 + rl;                       // m = b*4 + k
                int n = idxbB[m];
                size_t base = (size_t)(m >> 2) * OUT_STRIDE + 1
                            + (size_t)((n >> 4) * 4096 + (n & 15) * 16);
                #pragma unroll
                for (int j = 0; j < FJ; ++j)
                    __builtin_nontemporal_store(acc[i][j][r] + bv[j] + addc,
                        &outB[base + (size_t)((wn >> 4) + j) * 256 + lr]);
            }
    } else {
        #pragma unroll
        for (int j = 0; j < FJ; ++j) {
            int col = n0 + wn + j * 16 + lr;
            float bvv = bias[col];
            #pragma unroll
            for (int i = 0; i < FI; ++i) {
                #pragma unroll
                for (int r = 0; r < 4; ++r) {
                    int row = m0 + wm + i * 16 + quad * 4 + r;
                    float val = acc[i][j][r] + bvv;
                    ((ushort_t*)Cout)[(size_t)row * Nd + col] = f2bf(gelu_tanh(val));
                }
            }
        }
    }
}

extern "C" void kernel_launch(void* const* d_in, const int* in_sizes, int n_in,
                              void* d_out, int out_size, void* d_ws, size_t ws_size,
                              hipStream_t stream) {
    Params prm;
    prm.x     = (const float*)d_in[0];
    prm.in_g  = (const float*)d_in[1];
    prm.in_b  = (const float*)d_in[2];
    prm.nop_w = (const float*)d_in[3];
    prm.nop_b = (const float*)d_in[4];
    prm.c_w1  = (const float*)d_in[5];
    prm.c_b1  = (const float*)d_in[6];
    prm.c_w2  = (const float*)d_in[7];
    prm.c_b2  = (const float*)d_in[8];
    prm.c_w3  = (const float*)d_in[9];
    prm.c_b3  = (const float*)d_in[10];
    prm.emb   = (const float*)d_in[11];
    prm.emb_g = (const float*)d_in[12];
    prm.emb_b = (const float*)d_in[13];
    prm.f_w1  = (const float*)d_in[14];
    prm.f_b1  = (const float*)d_in[15];
    prm.f_w2  = (const float*)d_in[16];
    prm.f_b2  = (const float*)d_in[17];
    prm.f_w3  = (const float*)d_in[18];
    prm.f_b3  = (const float*)d_in[19];

    float* ws = (float*)d_ws;
    prm.coarse  = ws;                               // 2048*256 f32
    prm.xnsp    = (ushort_t*)(prm.coarse + 524288); // 2048*1024 bf16 [hi|lo]
    prm.h1sp    = prm.xnsp + 2097152;               // 2048*1024
    prm.h2sp    = prm.h1sp + 2097152;               // 2048*1024
    prm.e_bf    = prm.h2sp + 2097152;               // 8192*512
    prm.fh1_bf  = prm.e_bf + 4194304;               // 8192*512
    prm.fh2_bf  = prm.fh1_bf + 4194304;             // 8192*512
    prm.wt1     = prm.fh2_bf + 4194304;             // 512*1024
    prm.wt2     = prm.wt1 + 524288;                 // 512*512
    prm.wt3     = prm.wt2 + 262144;                 // 256*512
    prm.cwt1    = prm.wt3 + 131072;                 // 512*1024
    prm.cwt2    = prm.cwt1 + 524288;                // 512*1024
    prm.cwt3    = prm.cwt2 + 524288;                // 256*1024
    prm.idxb    = (int*)(prm.cwt3 + 262144);        // 8192
    prm.cvals   = (float*)(prm.idxb + 8192);        // 8192
    prm.out     = (float*)d_out;
    int* barcnt = (int*)(prm.cvals + 8192);         // 4 ints (grid barrier counter)

    // 0. zero barrier counter (workspace is poisoned each iteration)
    hipMemsetAsync(barcnt, 0, 16, stream);
    // 1. fused front-end: prep -> coarse MLP (3 layers) -> topk+embLN (+4096 bg units)
    fused_front_kernel<<<512, 256, 0, stream>>>(prm, barcnt);
    // 2. fh1 = gelu(concat(xn_hi, e) @ f_w1 + f_b1)  + bg-scatter units [4096, 16384)
    mfma_gemm_kernel<1, 64, 64, 0><<<dim3(8, 128 + 1536), 256, 0, stream>>>(
        prm.xnsp, prm.e_bf, prm.wt1, prm.f_b1, nullptr, prm.fh1_bf, 512, 1024,
        prm.coarse, prm.idxb, prm.out, 128, 4096);
    // 3. fh2 = gelu(fh1 @ f_w2 + f_b2)               + bg-scatter units [16384, 26624)
    mfma_gemm_kernel<0, 64, 64, 0><<<dim3(8, 128 + 1280), 256, 0, stream>>>(
        prm.fh1_bf, nullptr, prm.wt2, prm.f_b2, nullptr, prm.fh2_bf, 512, 512,
        prm.coarse, prm.idxb, prm.out, 128, 16384);
    // 4. cvals + log_softmax(fh2 @ f_w3 + f_b3) -> permuted out (top-k slabs)
    //    + bg-scatter units [26624, 32768)
    mfma_gemm_kernel<0, 32, 256, 3><<<dim3(1, 256 + 6144), 256, 0, stream>>>(
        prm.fh2_bf, nullptr, prm.wt3, prm.f_b3, prm.cvals, nullptr, 256, 512,
        prm.coarse, prm.idxb, prm.out, 256, 26624);
}

// Round 8
// 678.162 us; speedup vs baseline: 1.2895x; 1.2895x over previous
//
#include <hip/hip_runtime.h>
#include <math.h>

#define BATCH 2048
#define CH 512
#define N_COARSE 256
#define F_FINE 256
#define K_TOP 4
#define OUT_STRIDE 65537  // 1 + N*F

typedef unsigned short ushort_t;
typedef __bf16 bf16x8 __attribute__((ext_vector_type(8)));
typedef float f32x4 __attribute__((ext_vector_type(4)));

typedef __attribute__((address_space(3))) unsigned int lds_uint;
typedef __attribute__((address_space(1))) unsigned int gl_uint;

// async global->LDS, 16B per lane; LDS dest = wave-uniform base + lane*16
__device__ __forceinline__ void gload_lds16(const ushort_t* g, ushort_t* l) {
    __builtin_amdgcn_global_load_lds((const gl_uint*)g, (lds_uint*)l, 16, 0, 0);
}

__device__ __forceinline__ float gelu_tanh(float x) {
    float x3 = x * x * x;
    float t = tanhf(0.7978845608028654f * (x + 0.044715f * x3));
    return 0.5f * x * (1.0f + t);
}

__device__ __forceinline__ ushort_t f2bf(float f) {
    unsigned u = __float_as_uint(f);
    unsigned r = (u + 0x7FFF + ((u >> 16) & 1)) >> 16;
    return (ushort_t)r;
}
__device__ __forceinline__ float bf2f(ushort_t h) {
    return __uint_as_float(((unsigned)h) << 16);
}

struct Params {
    const float *x, *in_g, *in_b, *nop_w, *nop_b;
    const float *c_w1, *c_b1, *c_w2, *c_b2, *c_w3, *c_b3;
    const float *emb, *emb_g, *emb_b;
    const float *f_w1, *f_b1, *f_w2, *f_b2, *f_w3, *f_b3;
    float *coarse, *out, *cvals;
    ushort_t *xnsp, *h1sp, *h2sp, *e_bf, *fh1_bf, *fh2_bf;
    ushort_t *wt1, *wt2, *wt3, *cwt1, *cwt2, *cwt3;
    int *idxb;
};

// ---------------- prep: u<896 fine convT; u<1536 coarse convT hi/lo; else LN+no_op ----
__global__ __launch_bounds__(256) void prep_kernel(Params p) {
    __shared__ float s[32][33];
    int u = blockIdx.x, t = threadIdx.x;
    if (u < 1536) {
        const float* W; ushort_t* Wt; int Kd, Nd, gx, gy; bool split;
        if (u < 512)       { W=p.f_w1; Wt=p.wt1; Kd=1024; Nd=512; gx=u&15; gy=u>>4; split=false; }
        else if (u < 768)  { int v=u-512;  W=p.f_w2; Wt=p.wt2; Kd=512; Nd=512; gx=v&15; gy=v>>4; split=false; }
        else if (u < 896)  { int v=u-768;  W=p.f_w3; Wt=p.wt3; Kd=512; Nd=256; gx=v&7;  gy=v>>3; split=false; }
        else if (u < 1152) { int v=u-896;  W=p.c_w1; Wt=p.cwt1; Kd=512; Nd=512; gx=v&15; gy=v>>4; split=true; }
        else if (u < 1408) { int v=u-1152; W=p.c_w2; Wt=p.cwt2; Kd=512; Nd=512; gx=v&15; gy=v>>4; split=true; }
        else               { int v=u-1408; W=p.c_w3; Wt=p.cwt3; Kd=512; Nd=256; gx=v&7;  gy=v>>3; split=true; }
        int tx = t & 31, ty = t >> 5;
        int n0 = gx * 32, k0 = gy * 32;
        #pragma unroll
        for (int i = 0; i < 4; ++i) {
            int r = ty + i * 8;
            s[r][tx] = W[(size_t)(k0 + r) * Nd + n0 + tx];
        }
        __syncthreads();
        if (!split) {
            #pragma unroll
            for (int i = 0; i < 4; ++i) {
                int r = ty + i * 8;
                Wt[(size_t)(n0 + r) * Kd + k0 + tx] = f2bf(s[tx][r]);
            }
        } else {
            #pragma unroll
            for (int i = 0; i < 4; ++i) {
                int r = ty + i * 8;
                float v = s[tx][r];
                ushort_t h = f2bf(v);
                Wt[(size_t)(n0 + r) * 1024 + k0 + tx] = h;
                Wt[(size_t)(n0 + r) * 1024 + 512 + k0 + tx] = f2bf(v - bf2f(h));
            }
        }
    } else {
        float* red = &s[0][0];
        int row = u - 1536;
        int lane = t & 63, wave = t >> 6;
        const float* xr = p.x + (size_t)row * CH;
        float v0 = xr[t], v1 = xr[t + 256];
        float sm = v0 + v1, ss = v0 * v0 + v1 * v1;
        #pragma unroll
        for (int off = 32; off; off >>= 1) { sm += __shfl_xor(sm, off); ss += __shfl_xor(ss, off); }
        if (lane == 0) { red[wave] = sm; red[4 + wave] = ss; }
        __syncthreads();
        sm = red[0] + red[1] + red[2] + red[3];
        ss = red[4] + red[5] + red[6] + red[7];
        float mean = sm * (1.0f / CH);
        float var = ss * (1.0f / CH) - mean * mean;
        float rsq = rsqrtf(var + 1e-5f);
        float xn0 = (v0 - mean) * rsq * p.in_g[t] + p.in_b[t];
        float xn1 = (v1 - mean) * rsq * p.in_g[t + 256] + p.in_b[t + 256];
        ushort_t* xr2 = p.xnsp + (size_t)row * 1024;
        ushort_t h0 = f2bf(xn0), h1v = f2bf(xn1);
        xr2[t] = h0; xr2[t + 256] = h1v;
        xr2[512 + t] = f2bf(xn0 - bf2f(h0));
        xr2[512 + t + 256] = f2bf(xn1 - bf2f(h1v));
        float d = xn0 * p.nop_w[t] + xn1 * p.nop_w[t + 256];
        #pragma unroll
        for (int off = 32; off; off >>= 1) d += __shfl_xor(d, off);
        __syncthreads();
        if (lane == 0) red[wave] = d;
        __syncthreads();
        if (t == 0) p.out[(size_t)row * OUT_STRIDE] = red[0] + red[1] + red[2] + red[3] + p.nop_b[0];
    }
}

// ---- background scatter unit: one (b, cx) chunk of the permuted output ----
template<bool SKIP>
__device__ __forceinline__ void bg_scatter_unit(const float* __restrict__ coarse,
                                                const int* __restrict__ idxb,
                                                float* __restrict__ out, int gu) {
    const float LOG_F = 5.545177444479562f;
    int b = gu >> 4, cx = gu & 15, t = threadIdx.x;
    int4 ii = SKIP ? *(const int4*)&idxb[b * 4] : make_int4(-1, -1, -1, -1);
    size_t rowb = (size_t)b * OUT_STRIDE + 1;
    const float* cr = coarse + (size_t)b * N_COARSE;
    #pragma unroll
    for (int q = 0; q < 4; ++q) {
        int o = cx * 4096 + q * 1024 + t * 4;
        int n = ((o >> 12) << 4) | ((o >> 4) & 15);
        bool skip = SKIP && ((n == ii.x) | (n == ii.y) | (n == ii.z) | (n == ii.w));
        if (!skip) {
            float base = cr[n] - LOG_F;
            float* op = out + rowb + o;
            __builtin_nontemporal_store(base, op + 0);
            __builtin_nontemporal_store(base, op + 1);
            __builtin_nontemporal_store(base, op + 2);
            __builtin_nontemporal_store(base, op + 3);
        }
    }
}

// ---------------- bf16 MFMA GEMM, MTxNT tile, templated BK, global_load_lds dbuf ----------
// MODE 0: A1 row-major stride Ktot.  MODE 1: concat hi(xnsp)/e.  MODE 2: 3-term split K=1536.
// OUTM 0: bf16+gelu stride Nd. OUTM 1: split hi/lo bf16+gelu stride 1024.
// OUTM 2: f32. OUTM 3: cvals + log_softmax written directly to permuted out (NT==Nd==256).
// Blocks with blockIdx.y >= gemmY run background-scatter units instead (overlap BW w/ MFMA).
template<int MODE, int MT, int NT, int OUTM, int BK>
__global__ __launch_bounds__(256) void mfma_gemm_kernel(
    const ushort_t* __restrict__ A1, const ushort_t* __restrict__ A2,
    const ushort_t* __restrict__ Wt, const float* __restrict__ bias,
    const float* __restrict__ cvals, void* __restrict__ Cout, int Nd, int Ktot,
    const float* __restrict__ coarseB, const int* __restrict__ idxbB,
    float* __restrict__ outB, int gemmY, int suBase)
{
    if ((int)blockIdx.y >= gemmY) {
        int gu = suBase + ((int)blockIdx.y - gemmY) * (int)gridDim.x + (int)blockIdx.x;
        bg_scatter_unit<true>(coarseB, idxbB, outB, gu);
        return;
    }
    constexpr int FI = MT / 32, FJ = NT / 32;
    constexpr int LPR = BK / 8;         // 16B lane-loads per tile row
    constexpr int KS = BK / 32;         // 32-K MFMA slices per step
    __shared__ ushort_t As[2][MT * BK];
    __shared__ ushort_t Bs[2][NT * BK];
    __shared__ float mxs[64 * 2];
    __shared__ float ses[64 * 2];
    int t = threadIdx.x;
    int n0 = blockIdx.x * NT, m0 = blockIdx.y * MT;
    int wave = t >> 6, lane = t & 63;
    int wm = (wave & 1) * (MT / 2), wn = (wave >> 1) * (NT / 2);
    int lr = lane & 15, quad = lane >> 4;
    int wbase = wave * 64;   // wave-uniform LDS chunk base (lane-slots)

    f32x4 acc[FI][FJ] = {};

    // async stage tile k0 into LDS buffer pp (16B/lane, linear thread order)
    auto stageAB = [&](int k0, int pp) {
        int aoff = (MODE == 2) ? ((k0 >= 1024) ? k0 - 512 : (k0 & 511)) : k0;
        int woff = (MODE == 2) ? ((k0 >= 1024) ? k0 - 1024 : k0) : k0;
        constexpr int AL = MT * LPR;
        constexpr int BL = NT * LPR;
        if constexpr (AL >= 256) {
            #pragma unroll
            for (int i = 0; i < AL / 256; ++i) {
                int c = i * 256 + t, r = c / LPR, q = (c % LPR) * 8;
                int gr = m0 + r;
                const ushort_t* ap;
                if (MODE == 1)      ap = (k0 < 512) ? A1 + (size_t)(gr >> 2) * 1024 + k0 + q
                                                    : A2 + (size_t)gr * 512 + (k0 - 512) + q;
                else if (MODE == 2) ap = A1 + (size_t)gr * 1024 + aoff + q;
                else                ap = A1 + (size_t)gr * Ktot + k0 + q;
                gload_lds16(ap, &As[pp][(i * 256 + wbase) * 8]);
            }
        } else {
            if (t < AL) {            // waves 0..AL/64-1 stage A
                int r = t / LPR, q = (t % LPR) * 8;
                int gr = m0 + r;
                const ushort_t* ap;
                if (MODE == 1)      ap = (k0 < 512) ? A1 + (size_t)(gr >> 2) * 1024 + k0 + q
                                                    : A2 + (size_t)gr * 512 + (k0 - 512) + q;
                else if (MODE == 2) ap = A1 + (size_t)gr * 1024 + aoff + q;
                else                ap = A1 + (size_t)gr * Ktot + k0 + q;
                gload_lds16(ap, &As[pp][wbase * 8]);
            }
        }
        if constexpr (BL >= 256) {
            #pragma unroll
            for (int i = 0; i < BL / 256; ++i) {
                int c = i * 256 + t, r = c / LPR, q = (c % LPR) * 8;
                size_t wstride = (MODE == 2) ? 1024 : (size_t)Ktot;
                const ushort_t* bp = Wt + (size_t)(n0 + r) * wstride + woff + q;
                gload_lds16(bp, &Bs[pp][(i * 256 + wbase) * 8]);
            }
        } else {
            if (t < BL) {
                int r = t / LPR, q = (t % LPR) * 8;
                size_t wstride = (MODE == 2) ? 1024 : (size_t)Ktot;
                const ushort_t* bp = Wt + (size_t)(n0 + r) * wstride + woff + q;
                gload_lds16(bp, &Bs[pp][wbase * 8]);
            }
        }
    };

    stageAB(0, 0);
    int steps = Ktot / BK;
    int p = 0;
    for (int s = 0; s < steps; ++s) {
        __syncthreads();                       // drains vmcnt: buffer p is ready
        if (s + 1 < steps) stageAB((s + 1) * BK, p ^ 1);   // async into other buffer
        #pragma unroll
        for (int ks = 0; ks < KS; ++ks) {      // ascending K => identical accumulate order
            bf16x8 af[FI], bfr[FJ];
            #pragma unroll
            for (int i = 0; i < FI; ++i)
                af[i] = *(const bf16x8*)&As[p][(wm + i * 16 + lr) * BK + ks * 32 + quad * 8];
            #pragma unroll
            for (int j = 0; j < FJ; ++j)
                bfr[j] = *(const bf16x8*)&Bs[p][(wn + j * 16 + lr) * BK + ks * 32 + quad * 8];
            #pragma unroll
            for (int i = 0; i < FI; ++i)
                #pragma unroll
                for (int j = 0; j < FJ; ++j)
                    acc[i][j] = __builtin_amdgcn_mfma_f32_16x16x32_bf16(af[i], bfr[j], acc[i][j], 0, 0, 0);
        }
        p ^= 1;
    }

    if (OUTM == 3) {
        float bv[FJ];
        #pragma unroll
        for (int j = 0; j < FJ; ++j) bv[j] = bias[wn + j * 16 + lr];
        int half = wave >> 1;
        float rmx[FI][4];
        #pragma unroll
        for (int i = 0; i < FI; ++i)
            #pragma unroll
            for (int r = 0; r < 4; ++r) {
                float m = -1e30f;
                #pragma unroll
                for (int j = 0; j < FJ; ++j) m = fmaxf(m, acc[i][j][r] + bv[j]);
                #pragma unroll
                for (int mk = 1; mk < 16; mk <<= 1) m = fmaxf(m, __shfl_xor(m, mk));
                if (lr == 0) mxs[(wm + i * 16 + quad * 4 + r) * 2 + half] = m;
            }
        __syncthreads();
        #pragma unroll
        for (int i = 0; i < FI; ++i)
            #pragma unroll
            for (int r = 0; r < 4; ++r) {
                int rl = wm + i * 16 + quad * 4 + r;
                rmx[i][r] = fmaxf(mxs[rl * 2], mxs[rl * 2 + 1]);
            }
        #pragma unroll
        for (int i = 0; i < FI; ++i)
            #pragma unroll
            for (int r = 0; r < 4; ++r) {
                float sv = 0.f;
                #pragma unroll
                for (int j = 0; j < FJ; ++j) sv += expf(acc[i][j][r] + bv[j] - rmx[i][r]);
                #pragma unroll
                for (int mk = 1; mk < 16; mk <<= 1) sv += __shfl_xor(sv, mk);
                if (lr == 0) ses[(wm + i * 16 + quad * 4 + r) * 2 + half] = sv;
            }
        __syncthreads();
        #pragma unroll
        for (int i = 0; i < FI; ++i)
            #pragma unroll
            for (int r = 0; r < 4; ++r) {
                int rl = wm + i * 16 + quad * 4 + r;
                float se = ses[rl * 2] + ses[rl * 2 + 1];
                float addc = cvals[m0 + rl] - rmx[i][r] - logf(se);
                int m = m0 + rl;                       // m = b*4 + k
                int n = idxbB[m];
                size_t base = (size_t)(m >> 2) * OUT_STRIDE + 1
                            + (size_t)((n >> 4) * 4096 + (n & 15) * 16);
                #pragma unroll
                for (int j = 0; j < FJ; ++j)
                    __builtin_nontemporal_store(acc[i][j][r] + bv[j] + addc,
                        &outB[base + (size_t)((wn >> 4) + j) * 256 + lr]);
            }
    } else {
        #pragma unroll
        for (int j = 0; j < FJ; ++j) {
            int col = n0 + wn + j * 16 + lr;
            float bvv = bias[col];
            #pragma unroll
            for (int i = 0; i < FI; ++i) {
                #pragma unroll
                for (int r = 0; r < 4; ++r) {
                    int row = m0 + wm + i * 16 + quad * 4 + r;
                    float val = acc[i][j][r] + bvv;
                    if (OUTM == 0) {
                        ((ushort_t*)Cout)[(size_t)row * Nd + col] = f2bf(gelu_tanh(val));
                    } else if (OUTM == 1) {
                        float gv = gelu_tanh(val);
                        ushort_t h = f2bf(gv);
                        ((ushort_t*)Cout)[(size_t)row * 1024 + col] = h;
                        ((ushort_t*)Cout)[(size_t)row * 1024 + 512 + col] = f2bf(gv - bf2f(h));
                    } else {
                        ((float*)Cout)[(size_t)row * Nd + col] = val;
                    }
                }
            }
        }
    }
}

// ---------------- fused: top-4 per row + gather+LN of the 4 emb rows -> bf16 ----------------
// Blocks with blockIdx.x >= realX run background-scatter units (ALL slabs; no idxb dep —
// fh3's later dispatch overwrites the top-k slabs).
__global__ __launch_bounds__(256) void topk_embln_kernel(Params p, int realX) {
    if ((int)blockIdx.x >= realX) {
        bg_scatter_unit<false>(p.coarse, nullptr, p.out, (int)blockIdx.x - realX);
        return;
    }
    __shared__ int sidx[4];
    int brow = blockIdx.x, t = threadIdx.x;
    int wave = t >> 6, lane = t & 63;
    if (wave == 0) {
        const float* cr = p.coarse + (size_t)brow * N_COARSE;
        float v[4]; int id[4];
        #pragma unroll
        for (int j = 0; j < 4; ++j) { v[j] = cr[lane + 64 * j]; id[j] = lane + 64 * j; }
        #pragma unroll
        for (int r = 0; r < K_TOP; ++r) {
            float bv = v[0]; int bi = id[0];
            #pragma unroll
            for (int j = 1; j < 4; ++j)
                if (v[j] > bv || (v[j] == bv && id[j] < bi)) { bv = v[j]; bi = id[j]; }
            #pragma unroll
            for (int off = 32; off; off >>= 1) {
                float ov = __shfl_xor(bv, off); int oi = __shfl_xor(bi, off);
                if (ov > bv || (ov == bv && oi < bi)) { bv = ov; bi = oi; }
            }
            if ((bi & 63) == lane) v[bi >> 6] = -INFINITY;
            if (lane == 0) {
                sidx[r] = bi;
                p.idxb[brow * K_TOP + r] = bi;
                p.cvals[brow * K_TOP + r] = bv;
            }
        }
    }
    __syncthreads();
    int n = sidx[wave];
    const float* er = p.emb + (size_t)n * CH + lane * 8;
    float4 u0 = *(const float4*)er;
    float4 u1 = *(const float4*)(er + 4);
    float s  = u0.x + u0.y + u0.z + u0.w + u1.x + u1.y + u1.z + u1.w;
    float ss = u0.x * u0.x + u0.y * u0.y + u0.z * u0.z + u0.w * u0.w
             + u1.x * u1.x + u1.y * u1.y + u1.z * u1.z + u1.w * u1.w;
    #pragma unroll
    for (int off = 32; off; off >>= 1) { s += __shfl_xor(s, off); ss += __shfl_xor(ss, off); }
    float mean = s * (1.0f / CH);
    float var = ss * (1.0f / CH) - mean * mean;
    float rsq = rsqrtf(var + 1e-5f);
    float4 g0 = *(const float4*)(p.emb_g + lane * 8), g1 = *(const float4*)(p.emb_g + lane * 8 + 4);
    float4 b0 = *(const float4*)(p.emb_b + lane * 8), b1 = *(const float4*)(p.emb_b + lane * 8 + 4);
    uint4 pk;
    pk.x = (unsigned)f2bf((u0.x - mean) * rsq * g0.x + b0.x) |
           ((unsigned)f2bf((u0.y - mean) * rsq * g0.y + b0.y) << 16);
    pk.y = (unsigned)f2bf((u0.z - mean) * rsq * g0.z + b0.z) |
           ((unsigned)f2bf((u0.w - mean) * rsq * g0.w + b0.w) << 16);
    pk.z = (unsigned)f2bf((u1.x - mean) * rsq * g1.x + b1.x) |
           ((unsigned)f2bf((u1.y - mean) * rsq * g1.y + b1.y) << 16);
    pk.w = (unsigned)f2bf((u1.z - mean) * rsq * g1.z + b1.z) |
           ((unsigned)f2bf((u1.w - mean) * rsq * g1.w + b1.w) << 16);
    *(uint4*)(p.e_bf + (size_t)(brow * K_TOP + wave) * CH + lane * 8) = pk;
}

extern "C" void kernel_launch(void* const* d_in, const int* in_sizes, int n_in,
                              void* d_out, int out_size, void* d_ws, size_t ws_size,
                              hipStream_t stream) {
    Params prm;
    prm.x     = (const float*)d_in[0];
    prm.in_g  = (const float*)d_in[1];
    prm.in_b  = (const float*)d_in[2];
    prm.nop_w = (const float*)d_in[3];
    prm.nop_b = (const float*)d_in[4];
    prm.c_w1  = (const float*)d_in[5];
    prm.c_b1  = (const float*)d_in[6];
    prm.c_w2  = (const float*)d_in[7];
    prm.c_b2  = (const float*)d_in[8];
    prm.c_w3  = (const float*)d_in[9];
    prm.c_b3  = (const float*)d_in[10];
    prm.emb   = (const float*)d_in[11];
    prm.emb_g = (const float*)d_in[12];
    prm.emb_b = (const float*)d_in[13];
    prm.f_w1  = (const float*)d_in[14];
    prm.f_b1  = (const float*)d_in[15];
    prm.f_w2  = (const float*)d_in[16];
    prm.f_b2  = (const float*)d_in[17];
    prm.f_w3  = (const float*)d_in[18];
    prm.f_b3  = (const float*)d_in[19];

    float* ws = (float*)d_ws;
    prm.coarse  = ws;                               // 2048*256 f32
    prm.xnsp    = (ushort_t*)(prm.coarse + 524288); // 2048*1024 bf16 [hi|lo]
    prm.h1sp    = prm.xnsp + 2097152;               // 2048*1024
    prm.h2sp    = prm.h1sp + 2097152;               // 2048*1024
    prm.e_bf    = prm.h2sp + 2097152;               // 8192*512
    prm.fh1_bf  = prm.e_bf + 4194304;               // 8192*512
    prm.fh2_bf  = prm.fh1_bf + 4194304;             // 8192*512
    prm.wt1     = prm.fh2_bf + 4194304;             // 512*1024
    prm.wt2     = prm.wt1 + 524288;                 // 512*512
    prm.wt3     = prm.wt2 + 262144;                 // 256*512
    prm.cwt1    = prm.wt3 + 131072;                 // 512*1024
    prm.cwt2    = prm.cwt1 + 524288;                // 512*1024
    prm.cwt3    = prm.cwt2 + 524288;                // 256*1024
    prm.idxb    = (int*)(prm.cwt3 + 262144);        // 8192
    prm.cvals   = (float*)(prm.idxb + 8192);        // 8192
    prm.out     = (float*)d_out;

    const int NOSC = 1 << 28;  // "no scatter blocks" sentinel for gemmY

    // 1. fused prep: fine convT + coarse convT hi/lo + LN+no_op
    prep_kernel<<<3584, 256, 0, stream>>>(prm);
    // 2-4. coarse MLP via 3-term split-bf16 MFMA (K=1536); BK=128 -> 12 steps (4x fewer barriers)
    mfma_gemm_kernel<2, 32, 64, 1, 128><<<dim3(8, 64), 256, 0, stream>>>(
        prm.xnsp, nullptr, prm.cwt1, prm.c_b1, nullptr, prm.h1sp, 512, 1536,
        nullptr, nullptr, nullptr, NOSC, 0);
    mfma_gemm_kernel<2, 32, 64, 1, 128><<<dim3(8, 64), 256, 0, stream>>>(
        prm.h1sp, nullptr, prm.cwt2, prm.c_b2, nullptr, prm.h2sp, 512, 1536,
        nullptr, nullptr, nullptr, NOSC, 0);
    mfma_gemm_kernel<2, 32, 32, 2, 128><<<dim3(8, 64), 256, 0, stream>>>(
        prm.h2sp, nullptr, prm.cwt3, prm.c_b3, nullptr, prm.coarse, 256, 1536,
        nullptr, nullptr, nullptr, NOSC, 0);
    // 5. fused top-4 + emb gather+LN -> bf16   + bg-scatter units [0, 4096) (ALL slabs)
    topk_embln_kernel<<<BATCH + 4096, 256, 0, stream>>>(prm, BATCH);
    // 6. fh1 = gelu(concat(xn_hi, e) @ f_w1 + f_b1)  + bg-scatter units [4096, 16384)
    mfma_gemm_kernel<1, 64, 64, 0, 32><<<dim3(8, 128 + 1536), 256, 0, stream>>>(
        prm.xnsp, prm.e_bf, prm.wt1, prm.f_b1, nullptr, prm.fh1_bf, 512, 1024,
        prm.coarse, prm.idxb, prm.out, 128, 4096);
    // 7. fh2 = gelu(fh1 @ f_w2 + f_b2)               + bg-scatter units [16384, 26624)
    mfma_gemm_kernel<0, 64, 64, 0, 32><<<dim3(8, 128 + 1280), 256, 0, stream>>>(
        prm.fh1_bf, nullptr, prm.wt2, prm.f_b2, nullptr, prm.fh2_bf, 512, 512,
        prm.coarse, prm.idxb, prm.out, 128, 16384);
    // 8. cvals + log_softmax(fh2 @ f_w3 + f_b3) -> permuted out (top-k slabs)
    //    + bg-scatter units [26624, 32768)
    mfma_gemm_kernel<0, 32, 256, 3, 32><<<dim3(1, 256 + 6144), 256, 0, stream>>>(
        prm.fh2_bf, nullptr, prm.wt3, prm.f_b3, prm.cvals, nullptr, 256, 512,
        prm.coarse, prm.idxb, prm.out, 256, 26624);
}